// Round 6
// baseline (8748.450 us; speedup 1.0000x reference)
//
#include <hip/hip_runtime.h>
#include <hip/hip_bf16.h>

#define BATCH 2048
#define SEQ   80
#define EMBD  100
#define HU    512
#define NG    2048

typedef short bf16x8 __attribute__((ext_vector_type(8)));
typedef float f32x4  __attribute__((ext_vector_type(4)));
typedef int   i32x4  __attribute__((ext_vector_type(4)));

#define AS1(p) ((const __attribute__((address_space(1))) void*)(p))
#define AS3(p) ((__attribute__((address_space(3))) void*)(p))

// ---------------- prep kernels (proven, unchanged) ----------------
__global__ __launch_bounds__(256) void prep_emb(const float* __restrict__ emb,
                                                __hip_bfloat16* __restrict__ embp)
{
    int idx = blockIdx.x*256 + threadIdx.x;
    int row = idx >> 7, k = idx & 127;
    embp[idx] = __float2bfloat16(k < EMBD ? emb[row*EMBD + k] : 0.f);
}

// Gate-interleaved transposed weights. n = u*4 + g, col_orig = g*512 + u.
__global__ __launch_bounds__(256) void prep_wt(
    const float* __restrict__ W1, const float* __restrict__ U1, const float* __restrict__ b1,
    const float* __restrict__ W2, const float* __restrict__ U2, const float* __restrict__ b2,
    __hip_bfloat16* __restrict__ wt1, __hip_bfloat16* __restrict__ wt2,
    float* __restrict__ bp1, float* __restrict__ bp2)
{
    const int n = blockIdx.x;
    const int u = n >> 2, g = n & 3, col = g*HU + u;
    if (blockIdx.y == 0) {
        for (int k = threadIdx.x; k < 640; k += 256) {
            float v = (k < EMBD) ? W1[k*NG + col] : ((k < 128) ? 0.f : U1[(k-128)*NG + col]);
            wt1[n*640 + k] = __float2bfloat16(v);
        }
        if (threadIdx.x == 0) bp1[n] = b1[col];
    } else {
        for (int k = threadIdx.x; k < 1024; k += 256) {
            float v = (k < HU) ? W2[k*NG + col] : U2[(k-HU)*NG + col];
            wt2[n*1024 + k] = __float2bfloat16(v);
        }
        if (threadIdx.x == 0) bp2[n] = b2[col];
    }
}

// ---------------- persistent LSTM, XCD-partitioned ----------------
// 256 blocks, 512 thr, 1 block/CU (131KB LDS). XCD x = pair-group (x>>1: 512 rows)
// x (uh=x&1: 1024 gate-cols). 32 blocks/XCD: slot -> rB(4) x cB(8), tile 128x128.
// Weights: plain global_load_lds, L2-resident (3.4MB/XCD, never invalidated).
// h exchange: volatile(sc0sc1) restage -> per-XCD xst -> sc0(aux=1) reads.
__global__ __launch_bounds__(512, 1) void lstm_persist(
    const int* __restrict__ ids,
    const __hip_bfloat16* __restrict__ embp,
    const __hip_bfloat16* __restrict__ wt1, const float* __restrict__ bp1,
    const __hip_bfloat16* __restrict__ wt2, const float* __restrict__ bp2,
    __hip_bfloat16* __restrict__ h1ga, __hip_bfloat16* __restrict__ h1gb,
    __hip_bfloat16* __restrict__ h2ga, __hip_bfloat16* __restrict__ h2gb,
    __hip_bfloat16* __restrict__ xst,          // [8 xcd][2][512*512]
    unsigned* __restrict__ slotctr,            // [8]
    unsigned long long* __restrict__ xbars,    // [8]
    unsigned long long* __restrict__ pbars)    // [4]
{
    __shared__ __align__(16) unsigned short As[2][2][8192];  // [ks][buf] 16KB tiles
    __shared__ __align__(16) unsigned short Bs[2][2][8192];
    __shared__ int s_info;

    const int tid = threadIdx.x;
    if (tid == 0) {
        unsigned x = __builtin_amdgcn_s_getreg(63508) & 7u;  // HW_REG_XCC_ID(20), w32
        unsigned s = atomicAdd(&slotctr[x], 1u);
        s_info = (int)((x << 8) | (s & 31u));
    }
    __syncthreads();
    const int xcd  = (s_info >> 8) & 7;
    const int slot = s_info & 31;

    const int w    = tid >> 6;
    const int lane = tid & 63;
    const int l15  = lane & 15, tq = lane >> 4;
    const int ks   = w >> 2;            // K-split half
    const int wrow = (w >> 1) & 1, wcol = w & 1;
    const int ww   = w & 3;             // stager index within ks-group
    const int grp  = xcd >> 1, uh = xcd & 1;
    const int rB   = slot >> 3, cB = slot & 7;
    const int m0   = grp*512 + rB*128;  // global batch-row base
    const int n0   = uh*1024 + cB*128;  // global gate-col base
    const int lrow0 = rB*128;           // local row base within grp (xst indexing)
    const int ucol0 = n0 >> 2;          // global unit base

    __hip_bfloat16* xst1 = xst + (size_t)xcd * 2 * (512*512);
    __hip_bfloat16* xst2 = xst1 + 512*512;
    unsigned long long* xb = &xbars[xcd];
    unsigned long long* pb = &pbars[grp];

    f32x4 acc[4][4];
    float c1r[4][4][4] = {};            // cell state (valid on gq==1 lanes of ks0)
    float c2r[4][4][4] = {};

    auto bar = [&](unsigned long long* v, unsigned n){
        asm volatile("s_waitcnt vmcnt(0)" ::: "memory");
        __syncthreads();
        if (tid == 0) {
            unsigned long long old = __hip_atomic_fetch_add(v, 1ull,
                                        __ATOMIC_RELAXED, __HIP_MEMORY_SCOPE_AGENT);
            unsigned g = (unsigned)(old >> 32);
            if ((unsigned)(old & 0xffffffffull) == n - 1u)
                __hip_atomic_fetch_add(v, (1ull << 32) - (unsigned long long)n,
                                       __ATOMIC_RELAXED, __HIP_MEMORY_SCOPE_AGENT);
            else
                while ((unsigned)(__hip_atomic_load(v, __ATOMIC_RELAXED,
                                        __HIP_MEMORY_SCOPE_AGENT) >> 32) == g)
                    __builtin_amdgcn_s_sleep(8);
        }
        __syncthreads();
        asm volatile("" ::: "memory");
    };

    auto stageB = [&](const __hip_bfloat16* wt, int KTOT, int kt, unsigned short* Bd){
        #pragma unroll
        for (int j = 0; j < 4; ++j) {
            const int c = ww*4 + j;
            const int n = n0 + (c&7)*16 + l15;
            const int kk = kt*64 + (c>>3)*32 + tq*8;
            __builtin_amdgcn_global_load_lds(AS1(wt + (size_t)n*KTOT + kk),
                                             AS3(Bd + c*512), 16, 0, 0);
        }
    };
    auto stageA1 = [&](int kt, unsigned short* Ad, i32x4 idv){
        #pragma unroll
        for (int j = 0; j < 4; ++j) {
            const int c = ww*4 + j;
            const int row = (c&7)*16 + l15;
            const int kk = kt*64 + (c>>3)*32 + tq*8;
            if (kt < 2)
                __builtin_amdgcn_global_load_lds(AS1(embp + (size_t)idv[j]*128 + kk),
                                                 AS3(Ad + c*512), 16, 0, 0);
            else
                __builtin_amdgcn_global_load_lds(AS1(xst1 + (size_t)(lrow0+row)*HU + (kk-128)),
                                                 AS3(Ad + c*512), 16, 0, 1);   // sc0
        }
    };
    auto stageA2 = [&](int kt, unsigned short* Ad){
        #pragma unroll
        for (int j = 0; j < 4; ++j) {
            const int c = ww*4 + j;
            const int row = (c&7)*16 + l15;
            const int kk = kt*64 + (c>>3)*32 + tq*8;
            const __hip_bfloat16* src = (kt < 8) ? (xst1 + (size_t)(lrow0+row)*HU + kk)
                                                 : (xst2 + (size_t)(lrow0+row)*HU + (kk-512));
            __builtin_amdgcn_global_load_lds(AS1(src), AS3(Ad + c*512), 16, 0, 1);  // sc0
        }
    };

    auto mmakt = [&](const unsigned short* Ab, const unsigned short* Bb){
        #pragma unroll
        for (int s = 0; s < 2; ++s) {
            bf16x8 aF[4], bF[4];
            #pragma unroll
            for (int mi = 0; mi < 4; ++mi)
                aF[mi] = *(const bf16x8*)&Ab[(s*8 + wrow*4 + mi)*512 + tq*128 + l15*8];
            #pragma unroll
            for (int ni = 0; ni < 4; ++ni)
                bF[ni] = *(const bf16x8*)&Bb[(s*8 + wcol*4 + ni)*512 + tq*128 + l15*8];
            #pragma unroll
            for (int mi = 0; mi < 4; ++mi)
                #pragma unroll
                for (int ni = 0; ni < 4; ++ni)
                    acc[mi][ni] = __builtin_amdgcn_mfma_f32_16x16x32_bf16(
                                      aF[mi], bF[ni], acc[mi][ni], 0, 0, 0);
        }
    };

    auto kloop = [&](bool isl1, int NTh, i32x4 idv){
        #pragma unroll
        for (int mi = 0; mi < 4; ++mi)
            #pragma unroll
            for (int ni = 0; ni < 4; ++ni)
                acc[mi][ni] = (f32x4){0.f,0.f,0.f,0.f};
        const int ktf = ks * NTh;
        if (isl1) { stageA1(ktf, &As[ks][0][0], idv); stageB(wt1, 640,  ktf, &Bs[ks][0][0]); }
        else      { stageA2(ktf, &As[ks][0][0]);      stageB(wt2, 1024, ktf, &Bs[ks][0][0]); }
        __syncthreads();
        for (int i = 0; i < NTh; ++i) {
            const int buf = i & 1;
            if (i + 1 < NTh) {
                if (isl1) { stageA1(ktf+i+1, &As[ks][buf^1][0], idv);
                            stageB(wt1, 640,  ktf+i+1, &Bs[ks][buf^1][0]); }
                else      { stageA2(ktf+i+1, &As[ks][buf^1][0]);
                            stageB(wt2, 1024, ktf+i+1, &Bs[ks][buf^1][0]); }
            }
            mmakt(&As[ks][buf][0], &Bs[ks][buf][0]);
            __syncthreads();
        }
        // K-split merge: ks1 -> LDS -> ks0 accumulates
        float* mb = (float*)&As[0][0][0];
        const int wt4 = (wrow*2 + wcol) * 4096;
        if (ks == 1) {
            #pragma unroll
            for (int mi = 0; mi < 4; ++mi)
                #pragma unroll
                for (int ni = 0; ni < 4; ++ni)
                    *(f32x4*)(mb + wt4 + (mi*4+ni)*256 + lane*4) = acc[mi][ni];
        }
        __syncthreads();
        if (ks == 0) {
            #pragma unroll
            for (int mi = 0; mi < 4; ++mi)
                #pragma unroll
                for (int ni = 0; ni < 4; ++ni)
                    acc[mi][ni] += *(const f32x4*)(mb + wt4 + (mi*4+ni)*256 + lane*4);
        }
        __syncthreads();
    };

    // gates epilogue (ks0 waves): 4-lane group = i,f,g,o of one unit; h out volatile
    auto epilogue = [&](const float* bp, float (*cr)[4][4], __hip_bfloat16* hout){
        unsigned short* hs = &Bs[0][0][0];     // [128][40] ushorts (80B rows, 16B-aligned)
        const int gq = lane & 3;
        const bool isT = (gq == 2);
        if (ks == 0) {
            #pragma unroll
            for (int mi = 0; mi < 4; ++mi) {
                #pragma unroll
                for (int ni = 0; ni < 4; ++ni) {
                    const int nl = wcol*64 + ni*16 + l15;
                    const float bv = bp[n0 + nl];
                    const int ul = nl >> 2;
                    #pragma unroll
                    for (int rr = 0; rr < 4; ++rr) {
                        const int rowl = wrow*64 + mi*16 + tq*4 + rr;
                        const float z  = acc[mi][ni][rr] + bv;
                        const float zz = isT ? 2.f*z : z;
                        const float sg = 1.f/(1.f + __expf(-zz));
                        const float act = isT ? fmaf(2.f, sg, -1.f) : sg;  // tanh via sigm
                        const float act2 = __shfl_xor(act, 2);   // i<->g, f<->o
                        const float pig  = act * act2;           // gq0: sig(i)*tanh(g)
                        const float pig1 = __shfl_xor(pig, 1);   // gq1 <- gq0
                        const float cn  = fmaf(act, cr[mi][ni][rr], pig1); // gq1
                        const float tcn = fmaf(2.f, 1.f/(1.f + __expf(-2.f*cn)), -1.f);
                        const float tcn2 = __shfl_xor(tcn, 2);   // gq3 <- gq1
                        const float hv  = act * tcn2;            // gq3: sig(o)*tanh(c)
                        if (gq == 1) cr[mi][ni][rr] = cn;
                        if (gq == 3) {
                            __hip_bfloat16 hb = __float2bfloat16(hv);
                            hs[rowl*40 + ul] = *(unsigned short*)&hb;
                        }
                    }
                }
            }
        }
        __syncthreads();
        {
            const int row = tid >> 2, ch = tid & 3;
            i32x4 v = *(const i32x4*)(hs + row*40 + ch*8);
            *(volatile i32x4*)(hout + (size_t)(m0 + row)*HU + ucol0 + ch*8) = v;
        }
        __syncthreads();
    };

    for (int r = 0; r <= SEQ; ++r) {
        // ---- restage h1[r-1], h2[r-2] (volatile from MALL -> plain into XCD L2) ----
        const __hip_bfloat16* h1p  = ((r-1)&1) ? h1gb : h1ga;
        const __hip_bfloat16* h2pp = (r&1)     ? h2gb : h2ga;
        #pragma unroll
        for (int j = 0; j < 2; ++j) {
            const int idx = tid + j*512;
            const int lrow = slot*16 + (idx >> 6);
            const int uo = (idx & 63)*8;
            i32x4 v1 = *(const volatile i32x4*)(h1p  + (size_t)(grp*512 + lrow)*HU + uo);
            i32x4 v2 = *(const volatile i32x4*)(h2pp + (size_t)(grp*512 + lrow)*HU + uo);
            *(i32x4*)(xst1 + (size_t)lrow*HU + uo) = v1;
            *(i32x4*)(xst2 + (size_t)lrow*HU + uo) = v2;
        }
        bar(xb, 32);   // intra-XCD: xst ready in local L2

        if (r < SEQ) {
            i32x4 idv;
            #pragma unroll
            for (int j = 0; j < 4; ++j)
                idv[j] = ids[(m0 + ((ww&1)*4 + j)*16 + l15)*SEQ + r];
            kloop(true, 5, idv);
            epilogue(bp1, c1r, (r&1) ? h1gb : h1ga);
        }
        if (r >= 1) {
            kloop(false, 8, (i32x4){0,0,0,0});
            epilogue(bp2, c2r, ((r-1)&1) ? h2gb : h2ga);
        }
        bar(pb, 64);   // pair-scope: volatile h published for next round's restage
    }
}

// out[b] = sigmoid(h2[b,:] @ Wd + bd)
__global__ __launch_bounds__(256) void head_k(const __hip_bfloat16* __restrict__ h2,
    const float* __restrict__ Wd, const float* __restrict__ bd, float* __restrict__ out)
{
    const int b = blockIdx.x*4 + (threadIdx.x >> 6);
    const int lane = threadIdx.x & 63;
    float s = 0.f;
    #pragma unroll
    for (int u = lane; u < HU; u += 64) s += __bfloat162float(h2[b*HU + u]) * Wd[u];
    #pragma unroll
    for (int off = 32; off > 0; off >>= 1) s += __shfl_xor(s, off);
    if (lane == 0) out[b] = 1.f/(1.f + __expf(-(s + bd[0])));
}

extern "C" void kernel_launch(void* const* d_in, const int* in_sizes, int n_in,
                              void* d_out, int out_size, void* d_ws, size_t ws_size,
                              hipStream_t stream)
{
    const int*   ids = (const int*)  d_in[0];
    const float* emb = (const float*)d_in[1];
    const float* W1  = (const float*)d_in[2];
    const float* U1  = (const float*)d_in[3];
    const float* b1  = (const float*)d_in[4];
    const float* W2  = (const float*)d_in[5];
    const float* U2  = (const float*)d_in[6];
    const float* b2  = (const float*)d_in[7];
    const float* Wd  = (const float*)d_in[8];
    const float* bd  = (const float*)d_in[9];
    float* out = (float*)d_out;

    const size_t HS = (size_t)BATCH*HU;           // 1M elems (2MB bf16)
    char* p = (char*)d_ws;
    unsigned long long* pbars = (unsigned long long*)p;          // 4
    unsigned long long* xbars = (unsigned long long*)(p + 32);   // 8
    unsigned*           slotc = (unsigned*)(p + 96);             // 8
    p += 256;
    __hip_bfloat16* h1ga = (__hip_bfloat16*)p;  p += HS*2;
    __hip_bfloat16* h1gb = (__hip_bfloat16*)p;  p += HS*2;
    __hip_bfloat16* h2ga = (__hip_bfloat16*)p;  p += HS*2;
    __hip_bfloat16* h2gb = (__hip_bfloat16*)p;  p += HS*2;
    __hip_bfloat16* embp = (__hip_bfloat16*)p;  p += (size_t)10000*128*2;
    __hip_bfloat16* wt1  = (__hip_bfloat16*)p;  p += (size_t)2048*640*2;
    __hip_bfloat16* wt2  = (__hip_bfloat16*)p;  p += (size_t)2048*1024*2;
    float* bp1 = (float*)p;                     p += 2048*4;
    float* bp2 = (float*)p;                     p += 2048*4;
    __hip_bfloat16* xst  = (__hip_bfloat16*)p;  p += (size_t)8*2*512*512*2;

    // zero barriers, slot counters, and all h buffers every call (replay-safe)
    hipMemsetAsync(d_ws, 0, 256 + 4*HS*2, stream);

    prep_emb<<<10000*128/256, 256, 0, stream>>>(emb, embp);
    prep_wt<<<dim3(2048,2), 256, 0, stream>>>(W1,U1,b1,W2,U2,b2, wt1,wt2,bp1,bp2);

    lstm_persist<<<256, 512, 0, stream>>>(ids, embp, wt1, bp1, wt2, bp2,
                                          h1ga, h1gb, h2ga, h2gb,
                                          xst, slotc, xbars, pbars);

    // h2[79] lives in h2g[79&1] = h2gb
    head_k<<<BATCH/4, 256, 0, stream>>>(h2gb, Wd, bd, out);
}